// Round 7
// baseline (10379.510 us; speedup 1.0000x reference)
//
#include <hip/hip_runtime.h>
#include <hip/hip_cooperative_groups.h>
#include <math.h>

namespace cg = cooperative_groups;

#define DEV __device__ __forceinline__

typedef __attribute__((ext_vector_type(8))) short short8v;   // 8 bf16 = 4 VGPRs
typedef __attribute__((ext_vector_type(4))) float f32x4;

DEV float sigf(float x){ return 1.0f/(1.0f+__expf(-x)); }

DEV void split_bf16(float v, short& hi, short& lo){
  union { float f; unsigned u; } a; a.f = v;
  unsigned rh = (a.u + 0x7FFFu + ((a.u >> 16) & 1u)) >> 16;   // rne to bf16
  hi = (short)rh;
  union { unsigned u; float f; } b; b.u = rh << 16;
  a.f = v - b.f;
  unsigned rl = (a.u + 0x7FFFu + ((a.u >> 16) & 1u)) >> 16;
  lo = (short)rl;
}

// ---------------- embedding gather + split ----------------
__global__ __launch_bounds__(256) void k_embed_split(const int* __restrict__ tok,
    const float* __restrict__ emb, short* __restrict__ xH, short* __restrict__ xL){
  int i = blockIdx.x*256 + threadIdx.x;      // 512*64*64
  int bs = i >> 6, d = i & 63;
  float v = emb[(size_t)tok[bs]*64 + d];
  short h,l; split_bf16(v,h,l);
  xH[i]=h; xL[i]=l;
}

// ---------------- weight transpose + bf16 hi/lo split: W[K][2048] -> WT[2048][Ktot] ----
__global__ __launch_bounds__(256) void k_tsplit(const float* __restrict__ W,
    short* __restrict__ wth, short* __restrict__ wtl, int Ktot, int kbase){
  __shared__ float tile[32][33];
  int k0 = blockIdx.x*32, n0 = blockIdx.y*32;
  int tx = threadIdx.x & 31, ty = threadIdx.x >> 5;
  for (int r = ty; r < 32; r += 8)
    tile[r][tx] = W[(size_t)(k0+r)*2048 + n0 + tx];
  __syncthreads();
  for (int r = ty; r < 32; r += 8){
    int n = n0 + r;
    short hi, lo; split_bf16(tile[tx][r], hi, lo);
    size_t idx = (size_t)n*Ktot + kbase + k0 + tx;
    wth[idx] = hi; wtl[idx] = lo;
  }
}

// ---------------- persistent cooperative recurrence ----------------
struct SMemStage {
  union {
    struct {
      short Ah[64][40];          // [row][k], +8 pad (2-way banks = free)
      short Al[64][40];
      short Bh[128][40];         // [interleaved col][k]; col c = jj*4+gate
      short Bl[128][40];
    } st;
    float z[64][128];            // epilogue gate exchange
  };
};

struct RecStep {
  const short *a0H,*a0L,*a1H,*a1L,*a2H,*a2L;   // activation segments (bf16 hi/lo)
  int s0,s1,s2;                                // row strides (shorts)
  const short *wH,*wL;                         // WT [2048][KTOT]
  const float *bias;
  float *cst;                                  // cell state fp32, in-place
  short *oH,*oL;                               // h split output (row stride 512)
  float *ofp;                                  // optional fp32 h output
};

template<int KTOT>
DEV void rec_step(const RecStep& P, SMemStage& s, int m0, int j0, int tid){
  const int lane=tid&63, w=tid>>6, wr=w>>1, wc=w&1;
  const int cB=tid>>1, pB=tid&1;
  const int nB=(cB&3)*512 + j0 + (cB>>2);              // gate*512 + j0 + jj
  const short* wtB = (pB? P.wL : P.wH) + (size_t)nB*KTOT;
  const int rA=tid&63, pA=(tid>>6)&1;
  const bool doA = tid<128;
  const int arow = m0 + rA;
  const int fAr = wr*32 + (lane&15), fk=(lane>>4)*8;
  const int fBc = wc*64 + (lane&15);

  f32x4 acc[2][4];
  #pragma unroll
  for(int i=0;i<2;++i){
    #pragma unroll
    for(int j=0;j<4;++j) acc[i][j]=0.f;
  }

  auto abase=[&](int k0)->const short*{
    if (KTOT==576){
      if (k0<64) return (pA? P.a0L:P.a0H) + (size_t)arow*P.s0 + k0;
      return (pA? P.a1L:P.a1H) + (size_t)arow*P.s1 + (k0-64);
    } else {
      if (k0<512)  return (pA? P.a0L:P.a0H) + (size_t)arow*P.s0 + k0;
      if (k0<1024) return (pA? P.a1L:P.a1H) + (size_t)arow*P.s1 + (k0-512);
      return (pA? P.a2L:P.a2H) + (size_t)arow*P.s2 + (k0-1024);
    }
  };

  short8v bvv[4], avv[4];
  #pragma unroll
  for(int i=0;i<4;++i) bvv[i]=*(const short8v*)(wtB+i*8);
  if (doA){ const short* ap=abase(0);
    #pragma unroll
    for(int i=0;i<4;++i) avv[i]=*(const short8v*)(ap+i*8); }

  for (int k0=0;k0<KTOT;k0+=32){
    __syncthreads();
    { short (*Bp)[40] = pB ? s.st.Bl : s.st.Bh;
      #pragma unroll
      for(int i=0;i<4;++i) *(short8v*)&Bp[cB][i*8]=bvv[i];
      if (doA){ short (*Ap)[40] = pA ? s.st.Al : s.st.Ah;
        #pragma unroll
        for(int i=0;i<4;++i) *(short8v*)&Ap[rA][i*8]=avv[i]; } }
    __syncthreads();
    int kn=k0+32;
    if (kn<KTOT){
      #pragma unroll
      for(int i=0;i<4;++i) bvv[i]=*(const short8v*)(wtB+kn+i*8);
      if (doA){ const short* ap=abase(kn);
        #pragma unroll
        for(int i=0;i<4;++i) avv[i]=*(const short8v*)(ap+i*8); } }
    short8v ah[2],al[2],bh[4],bl[4];
    #pragma unroll
    for(int mf=0;mf<2;++mf){
      ah[mf]=*(const short8v*)&s.st.Ah[fAr+mf*16][fk];
      al[mf]=*(const short8v*)&s.st.Al[fAr+mf*16][fk]; }
    #pragma unroll
    for(int nf=0;nf<4;++nf){
      bh[nf]=*(const short8v*)&s.st.Bh[fBc+nf*16][fk];
      bl[nf]=*(const short8v*)&s.st.Bl[fBc+nf*16][fk]; }
    #pragma unroll
    for(int mf=0;mf<2;++mf){
      #pragma unroll
      for(int nf=0;nf<4;++nf){
        acc[mf][nf]=__builtin_amdgcn_mfma_f32_16x16x32_bf16(ah[mf],bh[nf],acc[mf][nf],0,0,0);
        acc[mf][nf]=__builtin_amdgcn_mfma_f32_16x16x32_bf16(ah[mf],bl[nf],acc[mf][nf],0,0,0);
        acc[mf][nf]=__builtin_amdgcn_mfma_f32_16x16x32_bf16(al[mf],bh[nf],acc[mf][nf],0,0,0);
      }
    }
  }

  __syncthreads();
  #pragma unroll
  for(int mf=0;mf<2;++mf){
    #pragma unroll
    for(int nf=0;nf<4;++nf){
      #pragma unroll
      for(int r=0;r<4;++r)
        s.z[wr*32+mf*16+(lane>>4)*4+r][wc*64+nf*16+(lane&15)] = acc[mf][nf][r];
    }
  }
  __syncthreads();
  {
    int row=tid>>2, jq=(tid&3)*8;
    size_t rbase=(size_t)(m0+row)*512 + j0;
    #pragma unroll
    for(int q=0;q<2;++q){
      int jj4=jq+q*4;
      float4 cold=*(const float4*)(P.cst+rbase+jj4);
      float co[4]={cold.x,cold.y,cold.z,cold.w};
      float hn[4],cn[4];
      #pragma unroll
      for(int e=0;e<4;++e){
        int jj=jj4+e, n=j0+jj;
        float4 zv=*(const float4*)&s.z[row][jj*4];
        float zi=zv.x+P.bias[n];
        float zf=zv.y+P.bias[512+n];
        float zg=zv.z+P.bias[1024+n];
        float zo=zv.w+P.bias[1536+n];
        float cc=sigf(zf)*co[e]+sigf(zi)*tanhf(zg);
        cn[e]=cc; hn[e]=sigf(zo)*tanhf(cc);
      }
      *(float4*)(P.cst+rbase+jj4)=make_float4(cn[0],cn[1],cn[2],cn[3]);
      short hh[4],hl[4];
      #pragma unroll
      for(int e=0;e<4;++e) split_bf16(hn[e],hh[e],hl[e]);
      *(short4*)(P.oH+rbase+jj4)=make_short4(hh[0],hh[1],hh[2],hh[3]);
      *(short4*)(P.oL+rbase+jj4)=make_short4(hl[0],hl[1],hl[2],hl[3]);
      if (P.ofp) *(float4*)(P.ofp+rbase+jj4)=make_float4(hn[0],hn[1],hn[2],hn[3]);
    }
  }
}

struct RecArgs {
  const short *xH,*xL;                      // [512,64,64] (b*4096 + s*64 + d)
  const short *w1H[2],*w1L[2];              // dir -> [2048][576]
  const short *w2H[2],*w2L[2];              // dir -> [2048][1536]
  const float *b1v[2],*b2v[2];
  short *f1H,*f1L,*g1H,*g1L;                // layer1 outputs [64][512][512] (f=dir0,g=dir1)
  const short *zeroS;                       // zeroed [512][512] shorts
  short *h2H[2][2],*h2L[2][2];              // [dir][pingpong]
  float *c1[2],*c2[2];
  float *h2out[2];                          // fp32 running final h per dir
};

__global__ __launch_bounds__(256) void k_recur(RecArgs A){
  cg::grid_group grid = cg::this_grid();
  __shared__ SMemStage s;
  const int tid=threadIdx.x;
  const int j0=blockIdx.x*32, m0=blockIdx.y*64, dir=blockIdx.z;
  const size_t SL=262144;   // 512*512
  short* outH = dir? A.g1H : A.f1H;
  short* outL = dir? A.g1L : A.f1L;
  // ---- layer 1 ----
  for (int t=0;t<64;++t){
    int sidx = dir? 63-t : t;
    RecStep P;
    P.a0H=A.xH + sidx*64; P.a0L=A.xL + sidx*64; P.s0=4096;
    if (t==0){ P.a1H=A.zeroS; P.a1L=A.zeroS; }
    else { int sp = dir? sidx+1 : sidx-1;
           P.a1H=outH + (size_t)sp*SL; P.a1L=outL + (size_t)sp*SL; }
    P.s1=512;
    P.a2H=nullptr; P.a2L=nullptr; P.s2=0;
    P.wH=A.w1H[dir]; P.wL=A.w1L[dir]; P.bias=A.b1v[dir];
    P.cst=A.c1[dir];
    P.oH=outH+(size_t)sidx*SL; P.oL=outL+(size_t)sidx*SL; P.ofp=nullptr;
    rec_step<576>(P,s,m0,j0,tid);
    grid.sync();
  }
  // ---- layer 2 ----
  for (int t=0;t<64;++t){
    int sidx = dir? 63-t : t;
    RecStep P;
    P.a0H=A.f1H+(size_t)sidx*SL; P.a0L=A.f1L+(size_t)sidx*SL; P.s0=512;
    P.a1H=A.g1H+(size_t)sidx*SL; P.a1L=A.g1L+(size_t)sidx*SL; P.s1=512;
    int pp=t&1;
    if (t==0){ P.a2H=A.zeroS; P.a2L=A.zeroS; }
    else { P.a2H=A.h2H[dir][pp^1]; P.a2L=A.h2L[dir][pp^1]; }
    P.s2=512;
    P.wH=A.w2H[dir]; P.wL=A.w2L[dir]; P.bias=A.b2v[dir];
    P.cst=A.c2[dir];
    P.oH=A.h2H[dir][pp]; P.oL=A.h2L[dir][pp]; P.ofp=A.h2out[dir];
    rec_step<1536>(P,s,m0,j0,tid);
    grid.sync();
  }
}

// ---------------- generic fp32 GEMM (head, small) ----------------
template<int ACT>
__global__ __launch_bounds__(256) void k_gemm(const float* __restrict__ A,
    const float* __restrict__ W, const float* __restrict__ bias,
    float* __restrict__ C, int K, int N){
  __shared__ float As[16][68];
  __shared__ float Ws[16][68];
  int tid=threadIdx.x;
  int m0=blockIdx.y*64, n0=blockIdx.x*64;
  int ar=tid>>2, akq=(tid&3)*4;
  int wk=tid>>4, wcq=(tid&15)*4;
  int ty=tid>>4, tx=tid&15;
  float acc[4][4];
  #pragma unroll
  for(int r=0;r<4;++r){
    #pragma unroll
    for(int c=0;c<4;++c) acc[r][c]=0.f; }
  for(int k0=0;k0<K;k0+=16){
    float4 av=*(const float4*)(A+(size_t)(m0+ar)*K+(k0+akq));
    float4 wv=*(const float4*)(W+(size_t)(k0+wk)*N+(n0+wcq));
    __syncthreads();
    As[akq+0][ar]=av.x; As[akq+1][ar]=av.y; As[akq+2][ar]=av.z; As[akq+3][ar]=av.w;
    *(float4*)&Ws[wk][wcq]=wv;
    __syncthreads();
    #pragma unroll
    for(int kk=0;kk<16;++kk){
      float4 a4=*(const float4*)&As[kk][ty*4];
      float4 b4=*(const float4*)&Ws[kk][tx*4];
      float a[4]={a4.x,a4.y,a4.z,a4.w};
      float b[4]={b4.x,b4.y,b4.z,b4.w};
      #pragma unroll
      for(int r=0;r<4;++r){
        #pragma unroll
        for(int c=0;c<4;++c) acc[r][c]+=a[r]*b[c]; }
    }
  }
  #pragma unroll
  for(int r=0;r<4;++r){
    int row=m0+ty*4+r;
    float o[4];
    #pragma unroll
    for(int c=0;c<4;++c){
      float v=acc[r][c]+bias[n0+tx*4+c];
      if(ACT==1) v=fmaxf(v,0.f);
      o[c]=v;
    }
    *(float4*)(C+(size_t)row*N+n0+tx*4) = make_float4(o[0],o[1],o[2],o[3]);
  }
}

__global__ __launch_bounds__(256) void k_concat(const float* __restrict__ hf,
    const float* __restrict__ hb, float* __restrict__ x2){
  int i = blockIdx.x*256+threadIdx.x;   // 512*1024
  int b = i>>10, j=i&1023;
  x2[i] = (j<512) ? hf[b*512+j] : hb[b*512 + (j-512)];
}

// ---------------- chunked memory read, phase 1 ----------------
__global__ __launch_bounds__(256) void k_mem_part(const float* __restrict__ query,
    const float* K0,const float* V0,const float* K1,const float* V1,
    const float* K2,const float* V2,const float* K3,const float* V3,
    const float* K4,const float* V4,const float* K5,const float* V5,
    float* __restrict__ parts){
  int chunk = blockIdx.x, b0 = blockIdx.y*8, tid = threadIdx.x;
  const float *Kp, *Vp; int mstart, mcnt;
  if      (chunk==0){ Kp=K0; Vp=V0; mstart=0;              mcnt=100; }
  else if (chunk<5) { Kp=K1; Vp=V1; mstart=(chunk-1)*250;  mcnt=250; }
  else if (chunk<7) { Kp=K2; Vp=V2; mstart=(chunk-5)*250;  mcnt=250; }
  else if (chunk==7){ Kp=K3; Vp=V3; mstart=0;              mcnt=100; }
  else if (chunk<48){ Kp=K4; Vp=V4; mstart=(chunk-8)*250;  mcnt=250; }
  else              { Kp=K5; Vp=V5; mstart=(chunk-48)*250; mcnt=250; }
  __shared__ float qs[8][64];
  __shared__ float p[8][256];
  __shared__ float red[4][8][64];
  __shared__ float mv[8], sv[8];
  ((float*)qs)[tid]     = query[(size_t)b0*64 + tid];
  ((float*)qs)[tid+256] = query[(size_t)b0*64 + 256 + tid];
  __syncthreads();
  float dot[8] = {0,0,0,0,0,0,0,0};
  if (tid < mcnt){
    const float4* kr = (const float4*)(Kp + (size_t)(mstart+tid)*64);
    #pragma unroll 4
    for (int i=0;i<16;++i){
      float4 kv = kr[i];
      #pragma unroll
      for (int mb=0;mb<8;++mb){
        float4 qv = *(const float4*)&qs[mb][i*4];
        dot[mb] += kv.x*qv.x + kv.y*qv.y + kv.z*qv.z + kv.w*qv.w;
      }
    }
  }
  #pragma unroll
  for (int mb=0;mb<8;++mb) p[mb][tid] = dot[mb]*0.125f;
  __syncthreads();
  {
    int mb = tid >> 5, l32 = tid & 31;
    float mx = -1e30f;
    #pragma unroll
    for (int j=0;j<8;++j){ int m = l32 + j*32; if (m < mcnt) mx = fmaxf(mx, p[mb][m]); }
    for (int d=16; d; d>>=1) mx = fmaxf(mx, __shfl_xor(mx, d, 32));
    float sum = 0.f;
    #pragma unroll
    for (int j=0;j<8;++j){ int m = l32 + j*32;
      if (m < mcnt){ float e = __expf(p[mb][m]-mx); p[mb][m]=e; sum+=e; } }
    for (int d=16; d; d>>=1) sum += __shfl_xor(sum, d, 32);
    if (l32==0){ mv[mb]=mx; sv[mb]=sum; }
  }
  __syncthreads();
  int d = tid & 63, g = tid >> 6;
  float pv[8] = {0,0,0,0,0,0,0,0};
  for (int m=g; m<mcnt; m+=4){
    float vv = Vp[(size_t)(mstart+m)*64 + d];
    #pragma unroll
    for (int mb=0;mb<8;++mb) pv[mb] += p[mb][m]*vv;
  }
  #pragma unroll
  for (int mb=0;mb<8;++mb) red[g][mb][d] = pv[mb];
  __syncthreads();
  for (int i=tid; i<512; i+=256){
    int mb = i >> 6, dd = i & 63;
    float tot = red[0][mb][dd]+red[1][mb][dd]+red[2][mb][dd]+red[3][mb][dd];
    parts[((size_t)(b0+mb)*50 + chunk)*68 + dd] = tot;
  }
  if (tid < 8){
    parts[((size_t)(b0+tid)*50 + chunk)*68 + 64] = mv[tid];
    parts[((size_t)(b0+tid)*50 + chunk)*68 + 65] = sv[tid];
  }
}

// ---------------- memory read, phase 2 ----------------
__global__ __launch_bounds__(64) void k_mem_comb(const float* __restrict__ query,
    const float* __restrict__ parts, float* __restrict__ reads){
  int b = blockIdx.x, d = threadIdx.x;
  const int c0s[6] = {0,1,5,7,8,48};
  const int c1s[6] = {1,5,7,8,48,50};
  float t = 0.f;
  #pragma unroll
  for (int i=0;i<6;++i) t += query[(size_t)b*64+i];
  float wt1 = sigf(t);
  for (int mem=0; mem<6; ++mem){
    float gmax = -1e30f;
    for (int c=c0s[mem]; c<c1s[mem]; ++c)
      gmax = fmaxf(gmax, parts[((size_t)b*50+c)*68 + 64]);
    float pv=0.f, tot=0.f;
    for (int c=c0s[mem]; c<c1s[mem]; ++c){
      const float* pc = parts + ((size_t)b*50+c)*68;
      float sc = __expf(pc[64]-gmax);
      pv  += sc*pc[d];
      tot += sc*pc[65];
    }
    float r = pv/tot * (mem==1 ? wt1 : 1.0f);
    reads[((size_t)mem*512+b)*64 + d] = r;
  }
}

__global__ __launch_bounds__(256) void k_meanreads(const float* __restrict__ reads,
    float* __restrict__ rmean){
  int i = blockIdx.x*256+threadIdx.x;   // 32768
  float sm=0.f;
  #pragma unroll
  for(int mem=0;mem<6;++mem) sm+=reads[(size_t)mem*32768 + i];
  rmean[i]=sm*(1.0f/6.0f);
}

__global__ __launch_bounds__(256) void k_bn(const float* __restrict__ x,
    const float* __restrict__ g,const float* __restrict__ b,
    const float* __restrict__ m,const float* __restrict__ v,
    float* __restrict__ y){
  int i=blockIdx.x*256+threadIdx.x;   // 262144
  int j=i&511;
  y[i] = g[j]*(x[i]-m[j])*rsqrtf(v[j]+1e-3f)+b[j];
}

__global__ __launch_bounds__(256) void k_final(const float* __restrict__ x6,
    const float* __restrict__ foW, const float* __restrict__ fob,
    float* __restrict__ out){
  int b = blockIdx.x*256+threadIdx.x;  // 512
  float acc=fob[0];
  #pragma unroll 4
  for(int k=0;k<128;++k) acc += x6[(size_t)b*128+k]*foW[k];
  out[b] = 1.0f/(1.0f+__expf(-acc));
}

extern "C" void kernel_launch(void* const* d_in, const int* in_sizes, int n_in,
                              void* d_out, int out_size, void* d_ws, size_t ws_size,
                              hipStream_t stream){
  const int*   tokens = (const int*)  d_in[0];
  const float* emb    = (const float*)d_in[1];
  const float* l1f_Wi=(const float*)d_in[2], *l1f_Wh=(const float*)d_in[3], *l1f_b=(const float*)d_in[4];
  const float* l1b_Wi=(const float*)d_in[5], *l1b_Wh=(const float*)d_in[6], *l1b_b=(const float*)d_in[7];
  const float* l2f_Wi=(const float*)d_in[8], *l2f_Wh=(const float*)d_in[9], *l2f_b=(const float*)d_in[10];
  const float* l2b_Wi=(const float*)d_in[11],*l2b_Wh=(const float*)d_in[12],*l2b_b=(const float*)d_in[13];
  // d_in[14..17] = Wq,bq,Wk,bk: dead (softmax over length-1 axis == 1, ctx == v)
  const float* Wv =(const float*)d_in[18], *bv =(const float*)d_in[19];
  const float* Wo =(const float*)d_in[20], *bo =(const float*)d_in[21];
  const float* mqW=(const float*)d_in[22], *mqb=(const float*)d_in[23];
  const float* extK =(const float*)d_in[24], *extV =(const float*)d_in[25];
  const float* formK=(const float*)d_in[26], *formV=(const float*)d_in[27];
  const float* concK=(const float*)d_in[28], *concV=(const float*)d_in[29];
  const float* stmK =(const float*)d_in[30], *stmV =(const float*)d_in[31];
  const float* ltmK =(const float*)d_in[32], *ltmV =(const float*)d_in[33];
  const float* infK =(const float*)d_in[34], *infV =(const float*)d_in[35];
  const float* rsW=(const float*)d_in[36], *rsb=(const float*)d_in[37];
  const float* bng=(const float*)d_in[38], *bnb=(const float*)d_in[39];
  const float* bnm=(const float*)d_in[40], *bnv=(const float*)d_in[41];
  const float* stW=(const float*)d_in[42], *stb=(const float*)d_in[43];
  const float* foW=(const float*)d_in[44], *fob=(const float*)d_in[45];
  float* out = (float*)d_out;

  char* p = (char*)d_ws;
  auto alloc = [&](size_t bytes)->void*{ void* r=p; p += (bytes + 255) & ~(size_t)255; return r; };

  // zero plane + cell states: contiguous, one memset
  short* zeroS = (short*)alloc(512*512*2);                  // 512 KB
  float* c1f = (float*)alloc(1<<20);
  float* c1b = (float*)alloc(1<<20);
  float* c2f = (float*)alloc(1<<20);
  float* c2b = (float*)alloc(1<<20);
  // activations (split planes)
  short* xH  = (short*)alloc((size_t)2097152*2);
  short* xL  = (short*)alloc((size_t)2097152*2);
  short* f1H = (short*)alloc((size_t)64*512*512*2);
  short* f1L = (short*)alloc((size_t)64*512*512*2);
  short* g1H = (short*)alloc((size_t)64*512*512*2);
  short* g1L = (short*)alloc((size_t)64*512*512*2);
  short* h2Hb[2][2]; short* h2Lb[2][2];
  for (int d=0; d<2; ++d)
    for (int q=0; q<2; ++q){ h2Hb[d][q]=(short*)alloc(512*512*2); h2Lb[d][q]=(short*)alloc(512*512*2); }
  float* h2o0 = (float*)alloc(1<<20);
  float* h2o1 = (float*)alloc(1<<20);
  // split weights
  short* w1H0=(short*)alloc((size_t)2048*576*2);  short* w1L0=(short*)alloc((size_t)2048*576*2);
  short* w1H1=(short*)alloc((size_t)2048*576*2);  short* w1L1=(short*)alloc((size_t)2048*576*2);
  short* w2H0=(short*)alloc((size_t)2048*1536*2); short* w2L0=(short*)alloc((size_t)2048*1536*2);
  short* w2H1=(short*)alloc((size_t)2048*1536*2); short* w2L1=(short*)alloc((size_t)2048*1536*2);
  // head scratch
  float* x2    = (float*)alloc((size_t)512*1024*4);
  float* vbuf  = (float*)alloc((size_t)512*512*4);
  float* x3    = (float*)alloc((size_t)512*1024*4);
  float* query = (float*)alloc((size_t)512*64*4);
  float* reads = (float*)alloc((size_t)6*512*64*4);
  float* rmean = (float*)alloc((size_t)512*64*4);
  float* x4    = (float*)alloc((size_t)512*512*4);
  float* x5    = (float*)alloc((size_t)512*512*4);
  float* x6    = (float*)alloc((size_t)512*128*4);
  float* parts = (float*)alloc((size_t)512*50*68*4);

  // zero: zero-plane + 4 cell states (contiguous)
  hipMemsetAsync(zeroS, 0, 512*512*2 + 4*(1<<20), stream);

  // weight transpose+split (once per launch)
  k_tsplit<<<dim3(2,64),  256, 0, stream>>>(l1f_Wi, w1H0, w1L0, 576, 0);
  k_tsplit<<<dim3(16,64), 256, 0, stream>>>(l1f_Wh, w1H0, w1L0, 576, 64);
  k_tsplit<<<dim3(2,64),  256, 0, stream>>>(l1b_Wi, w1H1, w1L1, 576, 0);
  k_tsplit<<<dim3(16,64), 256, 0, stream>>>(l1b_Wh, w1H1, w1L1, 576, 64);
  k_tsplit<<<dim3(32,64), 256, 0, stream>>>(l2f_Wi, w2H0, w2L0, 1536, 0);
  k_tsplit<<<dim3(16,64), 256, 0, stream>>>(l2f_Wh, w2H0, w2L0, 1536, 1024);
  k_tsplit<<<dim3(32,64), 256, 0, stream>>>(l2b_Wi, w2H1, w2L1, 1536, 0);
  k_tsplit<<<dim3(16,64), 256, 0, stream>>>(l2b_Wh, w2H1, w2L1, 1536, 1024);

  k_embed_split<<<2097152/256, 256, 0, stream>>>(tokens, emb, xH, xL);

  // persistent cooperative recurrence (both layers, both dirs)
  RecArgs ra;
  ra.xH=xH; ra.xL=xL;
  ra.w1H[0]=w1H0; ra.w1L[0]=w1L0; ra.w1H[1]=w1H1; ra.w1L[1]=w1L1;
  ra.w2H[0]=w2H0; ra.w2L[0]=w2L0; ra.w2H[1]=w2H1; ra.w2L[1]=w2L1;
  ra.b1v[0]=l1f_b; ra.b1v[1]=l1b_b; ra.b2v[0]=l2f_b; ra.b2v[1]=l2b_b;
  ra.f1H=f1H; ra.f1L=f1L; ra.g1H=g1H; ra.g1L=g1L;
  ra.zeroS=zeroS;
  for (int d=0; d<2; ++d)
    for (int q=0; q<2; ++q){ ra.h2H[d][q]=h2Hb[d][q]; ra.h2L[d][q]=h2Lb[d][q]; }
  ra.c1[0]=c1f; ra.c1[1]=c1b; ra.c2[0]=c2f; ra.c2[1]=c2b;
  ra.h2out[0]=h2o0; ra.h2out[1]=h2o1;
  void* kargs[] = { &ra };
  hipLaunchCooperativeKernel((void*)k_recur, dim3(16,8,2), dim3(256,1,1), kargs, 0, stream);

  // ---- head ----
  k_concat<<<524288/256, 256, 0, stream>>>(h2o0, h2o1, x2);
  k_gemm<0><<<dim3(8,8),  256, 0, stream>>>(x2,    Wv,  bv,  vbuf,  1024, 512);
  k_gemm<0><<<dim3(16,8), 256, 0, stream>>>(vbuf,  Wo,  bo,  x3,    512,  1024);
  k_gemm<0><<<dim3(1,8),  256, 0, stream>>>(x3,    mqW, mqb, query, 1024, 64);
  k_mem_part<<<dim3(50,64), 256, 0, stream>>>(query, extK,extV, formK,formV, concK,concV,
                                              stmK,stmV, ltmK,ltmV, infK,infV, parts);
  k_mem_comb<<<512, 64, 0, stream>>>(query, parts, reads);
  k_meanreads<<<32768/256, 256, 0, stream>>>(reads, rmean);
  k_gemm<1><<<dim3(8,8),  256, 0, stream>>>(rmean, rsW, rsb, x4,    64,   512);
  k_bn<<<262144/256, 256, 0, stream>>>(x4, bng, bnb, bnm, bnv, x5);
  k_gemm<0><<<dim3(2,8),  256, 0, stream>>>(x5,    stW, stb, x6,    512,  128);
  k_final<<<2, 256, 0, stream>>>(x6, foW, fob, out);
}